// Round 22
// baseline (172.611 us; speedup 1.0000x reference)
//
#include <hip/hip_runtime.h>
#include <hip/hip_bf16.h>

typedef __attribute__((ext_vector_type(8))) short short8;
typedef __attribute__((ext_vector_type(8))) unsigned short u16x8;
typedef __attribute__((ext_vector_type(4))) unsigned short u16x4;
typedef __attribute__((ext_vector_type(4))) float f32x4;
typedef __attribute__((ext_vector_type(16))) float f32x16;
typedef __attribute__((ext_vector_type(4))) int int4v;

#define S_  2048
#define D_  1024
#define F3  3072
#define QKLD 2048                  // qk buffer: row s -> [h][q 64 | k 64]
#define LOG2E 1.4426950408889634f
#define C_SCALE (0.125f * LOG2E)   // 1/sqrt(64) folded into exp2

__device__ __forceinline__ unsigned short f2bf(float f) {
  unsigned int u = __builtin_bit_cast(unsigned int, f);
  u += 0x7fffu + ((u >> 16) & 1u);
  return (unsigned short)(u >> 16);
}
__device__ __forceinline__ float fast_exp2(float x) {
  float r;
  asm("v_exp_f32 %0, %1" : "=v"(r) : "v"(x));
  return r;
}
__device__ __forceinline__ int cvtpk_bf16(float lo, float hi) {
  int r;
  asm("v_cvt_pk_bf16_f32 %0, %1, %2" : "=v"(r) : "v"(lo), "v"(hi));
  return r;
}
// C-layout (32x32, regs p0..p7 = half) -> MFMA B-operand frag, in-register (VERIFIED R8)
__device__ __forceinline__ short8 mkfrag(float p0, float p1, float p2, float p3,
                                         float p4, float p5, float p6, float p7) {
  int wA = cvtpk_bf16(p0, p1);
  int wB = cvtpk_bf16(p2, p3);
  int wC = cvtpk_bf16(p4, p5);
  int wD = cvtpk_bf16(p6, p7);
  asm volatile("v_permlane32_swap_b32 %0, %1" : "+v"(wA), "+v"(wC));
  asm volatile("v_permlane32_swap_b32 %0, %1" : "+v"(wB), "+v"(wD));
  int4v f = {wA, wB, wC, wD};
  return __builtin_bit_cast(short8, f);
}

// XOR swizzle for 128B LDS rows (8 x 16B chunks), 3-bit key
__device__ __forceinline__ int swz(int row, int col) {    // -> BYTE offset
  int byte = (row << 7) + (col << 1);
  return byte ^ ((((row & 7) ^ ((row >> 3) & 7)) << 4));
}
__device__ __forceinline__ unsigned short* ldsp(unsigned short* base, int byteoff) {
  return (unsigned short*)((char*)base + byteoff);
}

// ---- attn task tables (R17-verified): 8 balanced tasks per (bh,j), chunks <=11 ----
// mode: 0 = direct (normalized f32 -> out), 1 = chunk0 (UNNORMALIZED f32 -> out, +ml),
//       2 = chunkN (normalized bf16 -> scratch slot, +ml)
struct ATask { unsigned char qt, k0, k1, mode, mls, scr; };
__device__ __constant__ ATask g_tasks[8][8] = {
 {{0,0,1,0,0,0},{1,0,2,0,0,0},{31,0,11,1,0,0},{31,11,22,2,1,0},{31,22,32,2,2,1},{30,0,11,1,3,0},{30,11,21,2,4,2},{30,21,31,2,5,3}},
 {{2,0,3,0,0,0},{3,0,4,0,0,0},{29,0,10,1,0,0},{29,10,20,2,1,0},{29,20,30,2,2,1},{28,0,10,1,3,0},{28,10,20,2,4,2},{28,20,29,2,5,3}},
 {{4,0,5,0,0,0},{5,0,6,0,0,0},{27,0,10,1,0,0},{27,10,19,2,1,0},{27,19,28,2,2,1},{26,0,9,1,3,0},{26,9,18,2,4,2},{26,18,27,2,5,3}},
 {{6,0,7,0,0,0},{7,0,8,0,0,0},{25,0,9,1,0,0},{25,9,18,2,1,0},{25,18,26,2,2,1},{24,0,9,1,3,0},{24,9,17,2,4,2},{24,17,25,2,5,3}},
 {{8,0,9,0,0,0},{9,0,10,0,0,0},{23,0,8,1,0,0},{23,8,16,2,1,0},{23,16,24,2,2,1},{22,0,8,1,3,0},{22,8,16,2,4,2},{22,16,23,2,5,3}},
 {{10,0,6,1,0,0},{10,6,11,2,1,0},{11,0,6,1,2,0},{11,6,12,2,3,1},{21,0,11,1,4,0},{21,11,22,2,5,2},{20,0,11,1,6,0},{20,11,21,2,7,3}},
 {{12,0,7,1,0,0},{12,7,13,2,1,0},{13,0,7,1,2,0},{13,7,14,2,3,1},{19,0,10,1,4,0},{19,10,20,2,5,2},{18,0,10,1,6,0},{18,10,19,2,7,3}},
 {{14,0,8,1,0,0},{14,8,15,2,1,0},{15,0,8,1,2,0},{15,8,16,2,3,1},{17,0,9,1,4,0},{17,9,18,2,5,2},{16,0,9,1,6,0},{16,9,17,2,7,3}},
};
// merge table: one entry per chunked strip (22 per bh; qt 10..31 all covered)
struct MTask { unsigned char j, qt, nc, mlb, s0, s1; };
__device__ __constant__ MTask g_merge[22] = {
 {0,31,3,0,0,1},{0,30,3,3,2,3},
 {1,29,3,0,0,1},{1,28,3,3,2,3},
 {2,27,3,0,0,1},{2,26,3,3,2,3},
 {3,25,3,0,0,1},{3,24,3,3,2,3},
 {4,23,3,0,0,1},{4,22,3,3,2,3},
 {5,10,2,0,0,0},{5,11,2,2,1,0},{5,21,2,4,2,0},{5,20,2,6,3,0},
 {6,12,2,0,0,0},{6,13,2,2,1,0},{6,19,2,4,2,0},{6,18,2,6,3,0},
 {7,14,2,0,0,0},{7,15,2,2,1,0},{7,17,2,4,2,0},{7,16,2,6,3,0},
};

// ------- fused prep: x (f32)->bf16  +  W [1024][3072] -> Wt [3072][1024] bf16 -------
__global__ __launch_bounds__(256) void prep_kernel(const float* __restrict__ x,
                                                   unsigned short* __restrict__ xb,
                                                   const float* __restrict__ W,
                                                   unsigned short* __restrict__ Wt) {
  __shared__ float tile[64][65];
  const int bx = blockIdx.x;
  const int tid = threadIdx.x;
  if (bx < 4096) {
    int i = (bx * 256 + tid) * 4;
    f32x4 v = *reinterpret_cast<const f32x4*>(&x[i]);
    u16x4 o;
    o[0] = f2bf(v[0]); o[1] = f2bf(v[1]); o[2] = f2bf(v[2]); o[3] = f2bf(v[3]);
    *reinterpret_cast<u16x4*>(&xb[i]) = o;
  } else {
    int t = bx - 4096;                 // 0..767
    int nt = t % 48, kt = t / 48;
#pragma unroll
    for (int i = 0; i < 16; i++) {
      int idx = tid + i * 256;
      int r = idx >> 6, c = idx & 63;
      tile[r][c] = W[(size_t)(kt * 64 + r) * F3 + nt * 64 + c];
    }
    __syncthreads();
#pragma unroll
    for (int i = 0; i < 16; i++) {
      int idx = tid + i * 256;
      int rn = idx >> 6, ck = idx & 63;
      Wt[(size_t)(nt * 64 + rn) * D_ + kt * 64 + ck] = f2bf(tile[ck][rn]);
    }
  }
}

// ------- GEMM: 64x128 tile (6 blocks/CU), BK=64, R18-verified ------------------------
__global__ __launch_bounds__(256, 5) void qkv_gemm_kernel(const unsigned short* __restrict__ A,
                                                          const unsigned short* __restrict__ Bt,
                                                          const float* __restrict__ bias,
                                                          unsigned short* __restrict__ qk,
                                                          unsigned short* __restrict__ vT) {
  constexpr int K = D_;
  __shared__ unsigned short sA[64 * 64];     // 8 KB, rows 128B, swizzled
  __shared__ unsigned short sB[128 * 64];    // 16 KB
  int bm = blockIdx.x, bn = blockIdx.y;      // R18 order: consecutive blocks share Wt panel
  int tid = threadIdx.x;
  int wid = tid >> 6, lane = tid & 63;
  int wr = wid >> 1, wc = wid & 1;           // wr: 32-row half, wc: 64-col half
  int lh = lane >> 4, l15 = lane & 15;
  f32x4 acc[2][4] = {};

  const unsigned short* gA[2];
  const unsigned short* gB[4];
#pragma unroll
  for (int i = 0; i < 2; i++) {
    int c = tid + i * 256;
    int row = c >> 3;
    int key = (row ^ (row >> 3)) & 7;
    int col = ((c & 7) ^ key) * 8;
    gA[i] = &A[(size_t)(bm * 64 + row) * K + col];
  }
#pragma unroll
  for (int i = 0; i < 4; i++) {
    int c = tid + i * 256;
    int row = c >> 3;
    int key = (row ^ (row >> 3)) & 7;
    int col = ((c & 7) ^ key) * 8;
    gB[i] = &Bt[(size_t)(bn * 128 + row) * K + col];
  }

  for (int k0 = 0; k0 < K; k0 += 64) {
#pragma unroll
    for (int i = 0; i < 2; i++)
      __builtin_amdgcn_global_load_lds((const unsigned int*)(gA[i] + k0),
                                       (unsigned int*)(&sA[(i * 256 + wid * 64) * 8]), 16, 0, 0);
#pragma unroll
    for (int i = 0; i < 4; i++)
      __builtin_amdgcn_global_load_lds((const unsigned int*)(gB[i] + k0),
                                       (unsigned int*)(&sB[(i * 256 + wid * 64) * 8]), 16, 0, 0);
    asm volatile("s_waitcnt vmcnt(0)" ::: "memory");
    __syncthreads();

#pragma unroll
    for (int ksub = 0; ksub < 2; ksub++) {
      short8 af[2], bf[4];
#pragma unroll
      for (int m = 0; m < 2; m++) {
        int ar = wr * 32 + m * 16 + l15;     // 0..63
        int ab = (ar << 7) + ((((ksub << 2) | lh) ^ ((ar ^ (ar >> 3)) & 7)) << 4);
        af[m] = *reinterpret_cast<const short8*>((const char*)sA + ab);
      }
#pragma unroll
      for (int n = 0; n < 4; n++) {
        int br = wc * 64 + n * 16 + l15;     // 0..127
        int bb = (br << 7) + ((((ksub << 2) | lh) ^ ((br ^ (br >> 3)) & 7)) << 4);
        bf[n] = *reinterpret_cast<const short8*>((const char*)sB + bb);
      }
#pragma unroll
      for (int m = 0; m < 2; m++)
#pragma unroll
        for (int n = 0; n < 4; n++)
          acc[m][n] = __builtin_amdgcn_mfma_f32_16x16x32_bf16(af[m], bf[n], acc[m][n], 0, 0, 0);
    }
    __syncthreads();
  }

  int row0 = bm * 64 + wr * 32;
  int col0 = bn * 128 + wc * 64;
  const int bn3 = bn % 3;
  const int vside = (bn3 == 1) ? 0 : (bn3 == 2) ? 1 : -1;

  if (wc == vside) {
    unsigned short* tile = wr ? &sB[4096] : &sB[0];   // [64 d][64-frame, 32 s used]
    const int h = col0 / 192;
#pragma unroll
    for (int n = 0; n < 4; n++) {
      int d = n * 16 + l15;
      float bv = bias[col0 + n * 16 + l15];
#pragma unroll
      for (int m = 0; m < 2; m++) {
        u16x4 pk;
#pragma unroll
        for (int r = 0; r < 4; r++) pk[r] = f2bf(acc[m][n][r] + bv);
        *reinterpret_cast<u16x4*>(ldsp(tile, swz(d, m * 16 + lh * 4))) = pk;
      }
    }
    const int bbat = row0 >> 11, s0g = row0 & 2047;
    unsigned short* vrow = &vT[(size_t)(bbat * 16 + h) * 64 * S_ + s0g];
#pragma unroll
    for (int i = 0; i < 4; i++) {             // 64 d x 4 blks (32 s)
      int c = lane + i * 64;
      int d = c >> 2, blk = c & 3;
      short8 v = *reinterpret_cast<const short8*>(ldsp(tile, swz(d, blk * 8)));
      *reinterpret_cast<short8*>(&vrow[(size_t)d * S_ + blk * 8]) = v;
    }
  } else {
    // Q/K epilogue (R14-verified scalar stores)
#pragma unroll
    for (int n = 0; n < 4; n++) {
      int g = col0 + n * 16;
      int h = g / 192;
      int w = g % 192;
      float bv = bias[g + l15];
      int colq = h * 128 + w + l15;
#pragma unroll
      for (int m = 0; m < 2; m++)
#pragma unroll
        for (int r = 0; r < 4; r++) {
          int row = row0 + m * 16 + lh * 4 + r;
          qk[(size_t)row * QKLD + colq] = f2bf(acc[m][n][r] + bv);
        }
    }
  }
}

// -------- causal flash attention: R14 engine + R17 8-task table + bounds(128,4) ------
// The one delta vs R17: __launch_bounds__(128,4) -> 8 blocks/CU capacity, so all
// 8 tasks of a CU group are CO-RESIDENT (R17's (128,3) capped at 6 -> queueing broke
// co-residency + bh L2 grouping). 16 waves/CU = 4/SIMD for latency hiding.
struct Stage { u16x8 k[4]; u16x8 v[4]; };

__device__ __forceinline__ void stage_load(Stage& st, const unsigned short* kb,
                                           const unsigned short* vb, int tid) {
#pragma unroll
  for (int i = 0; i < 4; i++) {
    int c = tid + i * 128;
    int row = c >> 3, col = (c & 7) * 8;
    st.k[i] = *reinterpret_cast<const u16x8*>(kb + (size_t)row * QKLD + col);
    st.v[i] = *reinterpret_cast<const u16x8*>(vb + (size_t)row * S_ + col);
  }
}
__device__ __forceinline__ void stage_write(const Stage& st, unsigned short* sk,
                                            unsigned short* sv, int tid) {
#pragma unroll
  for (int i = 0; i < 4; i++) {
    int c = tid + i * 128;
    int row = c >> 3, col = (c & 7) * 8;
    *reinterpret_cast<u16x8*>(ldsp(sk, swz(row, col))) = st.k[i];
    *reinterpret_cast<u16x8*>(ldsp(sv, swz(row, col))) = st.v[i];
  }
}

__global__ __launch_bounds__(128, 4) void attn_kernel(const unsigned short* __restrict__ qk,
                                                      const unsigned short* __restrict__ vT,
                                                      unsigned short* __restrict__ Op,
                                                      float* __restrict__ ML,
                                                      float* __restrict__ out) {
  __shared__ unsigned short sK[4096];      // [64 k][64 d] swizzled (single buffer)
  __shared__ unsigned short sVt[4096];     // [64 d][64 k] swizzled

  const int lin = blockIdx.x;              // 0..2047
  const int cu = lin & 255;
  const int slot = lin >> 8;               // 0..7
  const int bh = cu >> 3;
  const int j = cu & 7;
  const ATask tk = g_tasks[j][slot];
  const int qt = tk.qt;
  const int k0 = tk.k0, k1 = tk.k1;

  const int b = bh >> 4, h = bh & 15;
  const int tid = threadIdx.x;
  const int wid = tid >> 6, lane = tid & 63;
  const int l31 = lane & 31, hi = lane >> 5;
  const int rowb = b * S_;

  const unsigned short* kptr = qk + (size_t)rowb * QKLD + h * 128 + 64 + (size_t)k0 * 64 * QKLD;
  const unsigned short* vptr = vT + (size_t)bh * 64 * S_ + k0 * 64;

  const int qrow = qt * 64 + wid * 32 + l31;

  short8 qf[4];
#pragma unroll
  for (int st = 0; st < 4; st++)
    qf[st] = *reinterpret_cast<const short8*>(
        qk + (size_t)(rowb + qrow) * QKLD + h * 128 + st * 16 + hi * 8);

  float m_s = -1e30f, l_s = 0.f;
  f32x16 o0, o1, zacc;
#pragma unroll
  for (int r = 0; r < 16; r++) { o0[r] = 0.f; o1[r] = 0.f; zacc[r] = 0.f; }

  Stage st;
  stage_load(st, kptr, vptr, tid);
  stage_write(st, sK, sVt, tid);
  __syncthreads();

  for (int t = k0; t < k1; t++) {
    if (t + 1 < k1) {
      kptr += (size_t)64 * QKLD;
      vptr += 64;
      stage_load(st, kptr, vptr, tid);
    }

    const bool diag = (t == qt);
    f32x16 s0, s1;
    __builtin_amdgcn_s_setprio(1);
    {
      short8 kf = *reinterpret_cast<const short8*>(ldsp(sK, swz(l31, hi * 8)));
      f32x16 a = __builtin_amdgcn_mfma_f32_32x32x16_bf16(kf, qf[0], zacc, 0, 0, 0);
#pragma unroll
      for (int stp = 1; stp < 4; stp++) {
        kf = *reinterpret_cast<const short8*>(ldsp(sK, swz(l31, stp * 16 + hi * 8)));
        a = __builtin_amdgcn_mfma_f32_32x32x16_bf16(kf, qf[stp], a, 0, 0, 0);
      }
      s0 = a;
    }
    if (!(diag && wid == 0)) {
      short8 kf = *reinterpret_cast<const short8*>(ldsp(sK, swz(32 + l31, hi * 8)));
      f32x16 a = __builtin_amdgcn_mfma_f32_32x32x16_bf16(kf, qf[0], zacc, 0, 0, 0);
#pragma unroll
      for (int stp = 1; stp < 4; stp++) {
        kf = *reinterpret_cast<const short8*>(ldsp(sK, swz(32 + l31, stp * 16 + hi * 8)));
        a = __builtin_amdgcn_mfma_f32_32x32x16_bf16(kf, qf[stp], a, 0, 0, 0);
      }
      s1 = a;
    } else {
#pragma unroll
      for (int r = 0; r < 16; r++) s1[r] = -1e30f;
    }
    __builtin_amdgcn_s_setprio(0);

    if (diag) {
      const int kb0 = t * 64;
      if (wid == 0) {
#pragma unroll
        for (int r = 0; r < 16; r++) {
          int kg = kb0 + (r & 3) + 8 * (r >> 2) + 4 * hi;
          if (kg > qrow) s0[r] = -1e30f;
        }
      } else {
#pragma unroll
        for (int r = 0; r < 16; r++) {
          int kg = kb0 + 32 + (r & 3) + 8 * (r >> 2) + 4 * hi;
          if (kg > qrow) s1[r] = -1e30f;
        }
      }
    }

    float mx = s0[0];
#pragma unroll
    for (int r = 1; r < 16; r++) mx = fmaxf(mx, s0[r]);
#pragma unroll
    for (int r = 0; r < 16; r++) mx = fmaxf(mx, s1[r]);
    mx = fmaxf(mx, __shfl_xor(mx, 32));

    if (!__all(mx <= m_s + 8.0f)) {   // defer-max, THR=8 raw-logit units (P <= e^1)
      float mnew = fmaxf(m_s, mx);
      float scl = fast_exp2((m_s - mnew) * C_SCALE);
      m_s = mnew;
      l_s *= scl;
#pragma unroll
      for (int r = 0; r < 16; r++) { o0[r] *= scl; o1[r] *= scl; }
    }

    const float mC = m_s * C_SCALE;
    float ps = 0.f;
#pragma unroll
    for (int r = 0; r < 16; r++) {
      s0[r] = fast_exp2(fmaf(s0[r], C_SCALE, -mC));
      ps += s0[r];
    }
#pragma unroll
    for (int r = 0; r < 16; r++) {
      s1[r] = fast_exp2(fmaf(s1[r], C_SCALE, -mC));
      ps += s1[r];
    }
    ps += __shfl_xor(ps, 32);
    l_s += ps;

    short8 pf[4];
    pf[0] = mkfrag(s0[0], s0[1], s0[2], s0[3], s0[4], s0[5], s0[6], s0[7]);
    pf[1] = mkfrag(s0[8], s0[9], s0[10], s0[11], s0[12], s0[13], s0[14], s0[15]);
    pf[2] = mkfrag(s1[0], s1[1], s1[2], s1[3], s1[4], s1[5], s1[6], s1[7]);
    pf[3] = mkfrag(s1[8], s1[9], s1[10], s1[11], s1[12], s1[13], s1[14], s1[15]);

    __builtin_amdgcn_s_setprio(1);
#pragma unroll
    for (int ks = 0; ks < 4; ks++) {
      short8 vf0 = *reinterpret_cast<const short8*>(
          ldsp(sVt, swz(l31, ks * 16 + hi * 8)));
      o0 = __builtin_amdgcn_mfma_f32_32x32x16_bf16(vf0, pf[ks], o0, 0, 0, 0);
      short8 vf1 = *reinterpret_cast<const short8*>(
          ldsp(sVt, swz(32 + l31, ks * 16 + hi * 8)));
      o1 = __builtin_amdgcn_mfma_f32_32x32x16_bf16(vf1, pf[ks], o1, 0, 0, 0);
    }
    __builtin_amdgcn_s_setprio(0);

    if (t + 1 < k1) {
      __syncthreads();                 // all waves done reading the buffer
      stage_write(st, sK, sVt, tid);
      __syncthreads();                 // writes visible
    }
  }

  if (tk.mode == 0) {
    // direct: normalized f32 -> out
    float invl = 1.f / l_s;
    float* op = &out[(size_t)(rowb + qrow) * D_ + h * 64];
#pragma unroll
    for (int rg = 0; rg < 4; rg++) {
      f32x4 v0, v1;
#pragma unroll
      for (int i = 0; i < 4; i++) {
        v0[i] = o0[rg * 4 + i] * invl;
        v1[i] = o1[rg * 4 + i] * invl;
      }
      *reinterpret_cast<f32x4*>(&op[rg * 8 + hi * 4]) = v0;
      *reinterpret_cast<f32x4*>(&op[32 + rg * 8 + hi * 4]) = v1;
    }
  } else {
    if (hi == 0) {
      float2* mlp = (float2*)ML;
      mlp[((bh * 8 + j) * 8 + tk.mls) * 64 + wid * 32 + l31] = make_float2(m_s, l_s);
    }
    if (tk.mode == 1) {
      // chunk0: UNNORMALIZED f32 -> out (exact; merge combines)
      float* op = &out[(size_t)(rowb + qrow) * D_ + h * 64];
#pragma unroll
      for (int rg = 0; rg < 4; rg++) {
        f32x4 v0, v1;
#pragma unroll
        for (int i = 0; i < 4; i++) { v0[i] = o0[rg * 4 + i]; v1[i] = o1[rg * 4 + i]; }
        *reinterpret_cast<f32x4*>(&op[rg * 8 + hi * 4]) = v0;
        *reinterpret_cast<f32x4*>(&op[32 + rg * 8 + hi * 4]) = v1;
      }
    } else {
      // chunkN: normalized bf16 -> scratch slot
      float invl = 1.f / l_s;
      unsigned short* po = Op + ((size_t)((bh * 8 + j) * 4 + tk.scr)) * 4096
                              + (size_t)(wid * 32 + l31) * 64;
#pragma unroll
      for (int rg = 0; rg < 4; rg++) {
        int d0 = rg * 8 + hi * 4;
        u16x4 a, c;
#pragma unroll
        for (int e = 0; e < 4; e++) {
          a[e] = f2bf(o0[rg * 4 + e] * invl);
          c[e] = f2bf(o1[rg * 4 + e] * invl);
        }
        *reinterpret_cast<u16x4*>(&po[d0]) = a;
        *reinterpret_cast<u16x4*>(&po[32 + d0]) = c;
      }
    }
  }
}

// -------- merge chunks of chunked strips (R17-verified, table-driven) --------
__global__ __launch_bounds__(256) void merge_kernel(const unsigned short* __restrict__ Op,
                                                    const float* __restrict__ ML,
                                                    float* __restrict__ out) {
  const int bid = blockIdx.x;               // 0..703 = 32 bh x 22 entries
  const int bh = bid / 22, e = bid % 22;
  const MTask mt = g_merge[e];
  const int b = bh >> 4, h = bh & 15;
  const int t = threadIdx.x;
  const int row = t >> 2, q4 = t & 3;       // 64 rows x 4 d-quarters

  const float2* mlp = (const float2*)ML;
  const int mlbase = (bh * 8 + mt.j) * 8;
  float2 ml0 = mlp[(mlbase + mt.mlb + 0) * 64 + row];
  float2 ml1 = mlp[(mlbase + mt.mlb + 1) * 64 + row];
  float m = fmaxf(ml0.x, ml1.x);
  float2 ml2 = make_float2(-1e30f, 0.f);
  if (mt.nc == 3) {
    ml2 = mlp[(mlbase + mt.mlb + 2) * 64 + row];
    m = fmaxf(m, ml2.x);
  }
  float w0 = fast_exp2((ml0.x - m) * C_SCALE);            // scales UNNORMALIZED O0
  float w1 = fast_exp2((ml1.x - m) * C_SCALE) * ml1.y;    // normalized-chunk weights
  float w2 = (mt.nc == 3) ? fast_exp2((ml2.x - m) * C_SCALE) * ml2.y : 0.f;
  float inv = 1.f / (ml0.y * w0 + w1 + w2);

  const int qrow = mt.qt * 64 + row;
  float* op = &out[(size_t)(b * S_ + qrow) * D_ + h * 64 + q4 * 16];
  const size_t sb = (size_t)((bh * 8 + mt.j) * 4);
  const unsigned short* p1 = Op + (sb + mt.s0) * 4096 + row * 64 + q4 * 16;
  const unsigned short* p2 = Op + (sb + mt.s1) * 4096 + row * 64 + q4 * 16;

#pragma unroll
  for (int g8 = 0; g8 < 2; g8++) {
    u16x8 a = *reinterpret_cast<const u16x8*>(p1 + g8 * 8);
    u16x8 c = *reinterpret_cast<const u16x8*>(p2 + g8 * 8);
    f32x4 r0, r1;
#pragma unroll
    for (int i = 0; i < 4; i++) {
      float base0 = op[g8 * 8 + i] * w0;
      float base1 = op[g8 * 8 + 4 + i] * w0;
      base0 += __builtin_bit_cast(float, (unsigned int)a[i] << 16) * w1;
      base1 += __builtin_bit_cast(float, (unsigned int)a[i + 4] << 16) * w1;
      if (mt.nc == 3) {
        base0 += __builtin_bit_cast(float, (unsigned int)c[i] << 16) * w2;
        base1 += __builtin_bit_cast(float, (unsigned int)c[i + 4] << 16) * w2;
      }
      r0[i] = base0 * inv;
      r1[i] = base1 * inv;
    }
    *reinterpret_cast<f32x4*>(&op[g8 * 8]) = r0;
    *reinterpret_cast<f32x4*>(&op[g8 * 8 + 4]) = r1;
  }
}

extern "C" void kernel_launch(void* const* d_in, const int* in_sizes, int n_in,
                              void* d_out, int out_size, void* d_ws, size_t ws_size,
                              hipStream_t stream) {
  const float* x    = (const float*)d_in[0];
  const float* W    = (const float*)d_in[1];
  const float* bias = (const float*)d_in[2];
  float* out = (float*)d_out;
  char* ws = (char*)d_ws;
  unsigned short* xb  = (unsigned short*)(ws);                    // 8 MB (reused as Op)
  unsigned short* wt  = (unsigned short*)(ws + (8u << 20));       // 6 MB (reused as ML)
  unsigned short* qk  = (unsigned short*)(ws + (14u << 20));      // 16 MB
  unsigned short* vTb = (unsigned short*)(ws + (30u << 20));      // 8 MB
  unsigned short* Op  = (unsigned short*)(ws);                    // 8 MB, after gemm done
  float* ML           = (float*)(ws + (8u << 20));                // 1 MB, after gemm done

  prep_kernel<<<4864, 256, 0, stream>>>(x, xb, W, wt);
  qkv_gemm_kernel<<<dim3(64, 24), 256, 0, stream>>>(xb, wt, bias, qk, vTb);
  attn_kernel<<<2048, 128, 0, stream>>>(qk, vTb, Op, ML, out);
  merge_kernel<<<704, 256, 0, stream>>>(Op, ML, out);
}

// Round 23
// 92.941 us; speedup vs baseline: 1.8572x; 1.8572x over previous
//
#include <hip/hip_runtime.h>
#include <hip/hip_bf16.h>

typedef __attribute__((ext_vector_type(8))) short short8;
typedef __attribute__((ext_vector_type(8))) unsigned short u16x8;
typedef __attribute__((ext_vector_type(4))) unsigned short u16x4;
typedef __attribute__((ext_vector_type(4))) float f32x4;
typedef __attribute__((ext_vector_type(16))) float f32x16;
typedef __attribute__((ext_vector_type(4))) int int4v;

#define S_  2048
#define D_  1024
#define F3  3072
#define QKLD 2048                  // qk buffer: row s -> [h][q 64 | k 64]
#define LOG2E 1.4426950408889634f
#define C_SCALE (0.125f * LOG2E)   // 1/sqrt(64) folded into exp2

__device__ __forceinline__ unsigned short f2bf(float f) {
  unsigned int u = __builtin_bit_cast(unsigned int, f);
  u += 0x7fffu + ((u >> 16) & 1u);
  return (unsigned short)(u >> 16);
}
__device__ __forceinline__ float fast_exp2(float x) {
  float r;
  asm("v_exp_f32 %0, %1" : "=v"(r) : "v"(x));
  return r;
}
__device__ __forceinline__ int cvtpk_bf16(float lo, float hi) {
  int r;
  asm("v_cvt_pk_bf16_f32 %0, %1, %2" : "=v"(r) : "v"(lo), "v"(hi));
  return r;
}
// C-layout (32x32, regs p0..p7 = half) -> MFMA B-operand frag, in-register (VERIFIED R8)
__device__ __forceinline__ short8 mkfrag(float p0, float p1, float p2, float p3,
                                         float p4, float p5, float p6, float p7) {
  int wA = cvtpk_bf16(p0, p1);
  int wB = cvtpk_bf16(p2, p3);
  int wC = cvtpk_bf16(p4, p5);
  int wD = cvtpk_bf16(p6, p7);
  asm volatile("v_permlane32_swap_b32 %0, %1" : "+v"(wA), "+v"(wC));
  asm volatile("v_permlane32_swap_b32 %0, %1" : "+v"(wB), "+v"(wD));
  int4v f = {wA, wB, wC, wD};
  return __builtin_bit_cast(short8, f);
}

// XOR swizzle for 128B LDS rows (8 x 16B chunks), 3-bit key
__device__ __forceinline__ int swz(int row, int col) {    // -> BYTE offset
  int byte = (row << 7) + (col << 1);
  return byte ^ ((((row & 7) ^ ((row >> 3) & 7)) << 4));
}
__device__ __forceinline__ unsigned short* ldsp(unsigned short* base, int byteoff) {
  return (unsigned short*)((char*)base + byteoff);
}

// ------- fused prep: x (f32)->bf16  +  W [1024][3072] -> Wt [3072][1024] bf16 -------
__global__ __launch_bounds__(256) void prep_kernel(const float* __restrict__ x,
                                                   unsigned short* __restrict__ xb,
                                                   const float* __restrict__ W,
                                                   unsigned short* __restrict__ Wt) {
  __shared__ float tile[64][65];
  const int bx = blockIdx.x;
  const int tid = threadIdx.x;
  if (bx < 4096) {
    int i = (bx * 256 + tid) * 4;
    f32x4 v = *reinterpret_cast<const f32x4*>(&x[i]);
    u16x4 o;
    o[0] = f2bf(v[0]); o[1] = f2bf(v[1]); o[2] = f2bf(v[2]); o[3] = f2bf(v[3]);
    *reinterpret_cast<u16x4*>(&xb[i]) = o;
  } else {
    int t = bx - 4096;                 // 0..767
    int nt = t % 48, kt = t / 48;
#pragma unroll
    for (int i = 0; i < 16; i++) {
      int idx = tid + i * 256;
      int r = idx >> 6, c = idx & 63;
      tile[r][c] = W[(size_t)(kt * 64 + r) * F3 + nt * 64 + c];
    }
    __syncthreads();
#pragma unroll
    for (int i = 0; i < 16; i++) {
      int idx = tid + i * 256;
      int rn = idx >> 6, ck = idx & 63;
      Wt[(size_t)(nt * 64 + rn) * D_ + kt * 64 + ck] = f2bf(tile[ck][rn]);
    }
  }
}

// ------- GEMM: 64x128 tile (6 blocks/CU), BK=64, R18-verified ------------------------
__global__ __launch_bounds__(256, 5) void qkv_gemm_kernel(const unsigned short* __restrict__ A,
                                                          const unsigned short* __restrict__ Bt,
                                                          const float* __restrict__ bias,
                                                          unsigned short* __restrict__ qk,
                                                          unsigned short* __restrict__ vT) {
  constexpr int K = D_;
  __shared__ unsigned short sA[64 * 64];     // 8 KB, rows 128B, swizzled
  __shared__ unsigned short sB[128 * 64];    // 16 KB
  int bm = blockIdx.x, bn = blockIdx.y;      // consecutive blocks share Wt panel (R18)
  int tid = threadIdx.x;
  int wid = tid >> 6, lane = tid & 63;
  int wr = wid >> 1, wc = wid & 1;           // wr: 32-row half, wc: 64-col half
  int lh = lane >> 4, l15 = lane & 15;
  f32x4 acc[2][4] = {};

  const unsigned short* gA[2];
  const unsigned short* gB[4];
#pragma unroll
  for (int i = 0; i < 2; i++) {
    int c = tid + i * 256;
    int row = c >> 3;
    int key = (row ^ (row >> 3)) & 7;
    int col = ((c & 7) ^ key) * 8;
    gA[i] = &A[(size_t)(bm * 64 + row) * K + col];
  }
#pragma unroll
  for (int i = 0; i < 4; i++) {
    int c = tid + i * 256;
    int row = c >> 3;
    int key = (row ^ (row >> 3)) & 7;
    int col = ((c & 7) ^ key) * 8;
    gB[i] = &Bt[(size_t)(bn * 128 + row) * K + col];
  }

  for (int k0 = 0; k0 < K; k0 += 64) {
#pragma unroll
    for (int i = 0; i < 2; i++)
      __builtin_amdgcn_global_load_lds((const unsigned int*)(gA[i] + k0),
                                       (unsigned int*)(&sA[(i * 256 + wid * 64) * 8]), 16, 0, 0);
#pragma unroll
    for (int i = 0; i < 4; i++)
      __builtin_amdgcn_global_load_lds((const unsigned int*)(gB[i] + k0),
                                       (unsigned int*)(&sB[(i * 256 + wid * 64) * 8]), 16, 0, 0);
    asm volatile("s_waitcnt vmcnt(0)" ::: "memory");
    __syncthreads();

#pragma unroll
    for (int ksub = 0; ksub < 2; ksub++) {
      short8 af[2], bf[4];
#pragma unroll
      for (int m = 0; m < 2; m++) {
        int ar = wr * 32 + m * 16 + l15;     // 0..63
        int ab = (ar << 7) + ((((ksub << 2) | lh) ^ ((ar ^ (ar >> 3)) & 7)) << 4);
        af[m] = *reinterpret_cast<const short8*>((const char*)sA + ab);
      }
#pragma unroll
      for (int n = 0; n < 4; n++) {
        int br = wc * 64 + n * 16 + l15;     // 0..127
        int bb = (br << 7) + ((((ksub << 2) | lh) ^ ((br ^ (br >> 3)) & 7)) << 4);
        bf[n] = *reinterpret_cast<const short8*>((const char*)sB + bb);
      }
#pragma unroll
      for (int m = 0; m < 2; m++)
#pragma unroll
        for (int n = 0; n < 4; n++)
          acc[m][n] = __builtin_amdgcn_mfma_f32_16x16x32_bf16(af[m], bf[n], acc[m][n], 0, 0, 0);
    }
    __syncthreads();
  }

  int row0 = bm * 64 + wr * 32;
  int col0 = bn * 128 + wc * 64;
  const int bn3 = bn % 3;
  const int vside = (bn3 == 1) ? 0 : (bn3 == 2) ? 1 : -1;

  if (wc == vside) {
    unsigned short* tile = wr ? &sB[4096] : &sB[0];   // [64 d][64-frame, 32 s used]
    const int h = col0 / 192;
#pragma unroll
    for (int n = 0; n < 4; n++) {
      int d = n * 16 + l15;
      float bv = bias[col0 + n * 16 + l15];
#pragma unroll
      for (int m = 0; m < 2; m++) {
        u16x4 pk;
#pragma unroll
        for (int r = 0; r < 4; r++) pk[r] = f2bf(acc[m][n][r] + bv);
        *reinterpret_cast<u16x4*>(ldsp(tile, swz(d, m * 16 + lh * 4))) = pk;
      }
    }
    const int bbat = row0 >> 11, s0g = row0 & 2047;
    unsigned short* vrow = &vT[(size_t)(bbat * 16 + h) * 64 * S_ + s0g];
#pragma unroll
    for (int i = 0; i < 4; i++) {             // 64 d x 4 blks (32 s)
      int c = lane + i * 64;
      int d = c >> 2, blk = c & 3;
      short8 v = *reinterpret_cast<const short8*>(ldsp(tile, swz(d, blk * 8)));
      *reinterpret_cast<short8*>(&vrow[(size_t)d * S_ + blk * 8]) = v;
    }
  } else {
    // Q/K epilogue (R14-verified scalar stores)
#pragma unroll
    for (int n = 0; n < 4; n++) {
      int g = col0 + n * 16;
      int h = g / 192;
      int w = g % 192;
      float bv = bias[g + l15];
      int colq = h * 128 + w + l15;
#pragma unroll
      for (int m = 0; m < 2; m++)
#pragma unroll
        for (int r = 0; r < 4; r++) {
          int row = row0 + m * 16 + lh * 4 + r;
          qk[(size_t)row * QKLD + colq] = f2bf(acc[m][n][r] + bv);
        }
    }
  }
}

// -------- causal flash attention: R14-verified (k-chunked tasks, defer-max THR=8) ----
struct Stage { u16x8 k[4]; u16x8 v[4]; };

__device__ __forceinline__ void stage_load(Stage& st, const unsigned short* kb,
                                           const unsigned short* vb, int tid) {
#pragma unroll
  for (int i = 0; i < 4; i++) {
    int c = tid + i * 128;
    int row = c >> 3, col = (c & 7) * 8;
    st.k[i] = *reinterpret_cast<const u16x8*>(kb + (size_t)row * QKLD + col);
    st.v[i] = *reinterpret_cast<const u16x8*>(vb + (size_t)row * S_ + col);
  }
}
__device__ __forceinline__ void stage_write(const Stage& st, unsigned short* sk,
                                            unsigned short* sv, int tid) {
#pragma unroll
  for (int i = 0; i < 4; i++) {
    int c = tid + i * 128;
    int row = c >> 3, col = (c & 7) * 8;
    *reinterpret_cast<u16x8*>(ldsp(sk, swz(row, col))) = st.k[i];
    *reinterpret_cast<u16x8*>(ldsp(sv, swz(row, col))) = st.v[i];
  }
}

__global__ __launch_bounds__(128, 3) void attn_kernel(const unsigned short* __restrict__ qk,
                                                      const unsigned short* __restrict__ vT,
                                                      unsigned short* __restrict__ Op,
                                                      float* __restrict__ ML,
                                                      float* __restrict__ out) {
  __shared__ unsigned short sK[4096];      // [64 k][64 d] swizzled (single buffer)
  __shared__ unsigned short sVt[4096];     // [64 d][64 k] swizzled

  const int lin = blockIdx.x;
  const int cu = lin & 255;
  const int slot = lin >> 8;
  const int bh = cu >> 3;
  const int j = cu & 7;
  int qt, k0, k1, chunk;
  if (slot < 2) {
    qt = 2 * j + slot; k0 = 0; k1 = qt + 1; chunk = -1;
  } else {
    qt = (slot < 4) ? (31 - 2 * j) : (30 - 2 * j);
    int T = qt + 1, half = (T + 1) >> 1;
    if ((slot & 1) == 0) { k0 = 0; k1 = half; chunk = 0; }
    else                 { k0 = half; k1 = T; chunk = 1; }
  }

  const int b = bh >> 4, h = bh & 15;
  const int tid = threadIdx.x;
  const int wid = tid >> 6, lane = tid & 63;
  const int l31 = lane & 31, hi = lane >> 5;
  const int rowb = b * S_;

  const unsigned short* kptr = qk + (size_t)rowb * QKLD + h * 128 + 64 + (size_t)k0 * 64 * QKLD;
  const unsigned short* vptr = vT + (size_t)bh * 64 * S_ + k0 * 64;

  const int qrow = qt * 64 + wid * 32 + l31;

  short8 qf[4];
#pragma unroll
  for (int st = 0; st < 4; st++)
    qf[st] = *reinterpret_cast<const short8*>(
        qk + (size_t)(rowb + qrow) * QKLD + h * 128 + st * 16 + hi * 8);

  float m_s = -1e30f, l_s = 0.f;
  f32x16 o0, o1, zacc;
#pragma unroll
  for (int r = 0; r < 16; r++) { o0[r] = 0.f; o1[r] = 0.f; zacc[r] = 0.f; }

  Stage st;
  stage_load(st, kptr, vptr, tid);
  stage_write(st, sK, sVt, tid);
  __syncthreads();

  for (int t = k0; t < k1; t++) {
    if (t + 1 < k1) {
      kptr += (size_t)64 * QKLD;
      vptr += 64;
      stage_load(st, kptr, vptr, tid);
    }

    const bool diag = (t == qt);
    f32x16 s0, s1;
    __builtin_amdgcn_s_setprio(1);
    {
      short8 kf = *reinterpret_cast<const short8*>(ldsp(sK, swz(l31, hi * 8)));
      f32x16 a = __builtin_amdgcn_mfma_f32_32x32x16_bf16(kf, qf[0], zacc, 0, 0, 0);
#pragma unroll
      for (int stp = 1; stp < 4; stp++) {
        kf = *reinterpret_cast<const short8*>(ldsp(sK, swz(l31, stp * 16 + hi * 8)));
        a = __builtin_amdgcn_mfma_f32_32x32x16_bf16(kf, qf[stp], a, 0, 0, 0);
      }
      s0 = a;
    }
    if (!(diag && wid == 0)) {
      short8 kf = *reinterpret_cast<const short8*>(ldsp(sK, swz(32 + l31, hi * 8)));
      f32x16 a = __builtin_amdgcn_mfma_f32_32x32x16_bf16(kf, qf[0], zacc, 0, 0, 0);
#pragma unroll
      for (int stp = 1; stp < 4; stp++) {
        kf = *reinterpret_cast<const short8*>(ldsp(sK, swz(32 + l31, stp * 16 + hi * 8)));
        a = __builtin_amdgcn_mfma_f32_32x32x16_bf16(kf, qf[stp], a, 0, 0, 0);
      }
      s1 = a;
    } else {
#pragma unroll
      for (int r = 0; r < 16; r++) s1[r] = -1e30f;
    }
    __builtin_amdgcn_s_setprio(0);

    if (diag) {
      const int kb0 = t * 64;
      if (wid == 0) {
#pragma unroll
        for (int r = 0; r < 16; r++) {
          int kg = kb0 + (r & 3) + 8 * (r >> 2) + 4 * hi;
          if (kg > qrow) s0[r] = -1e30f;
        }
      } else {
#pragma unroll
        for (int r = 0; r < 16; r++) {
          int kg = kb0 + 32 + (r & 3) + 8 * (r >> 2) + 4 * hi;
          if (kg > qrow) s1[r] = -1e30f;
        }
      }
    }

    float mx = s0[0];
#pragma unroll
    for (int r = 1; r < 16; r++) mx = fmaxf(mx, s0[r]);
#pragma unroll
    for (int r = 0; r < 16; r++) mx = fmaxf(mx, s1[r]);
    mx = fmaxf(mx, __shfl_xor(mx, 32));

    if (!__all(mx <= m_s + 8.0f)) {   // defer-max, THR=8 raw-logit units (P <= e^1)
      float mnew = fmaxf(m_s, mx);
      float scl = fast_exp2((m_s - mnew) * C_SCALE);
      m_s = mnew;
      l_s *= scl;
#pragma unroll
      for (int r = 0; r < 16; r++) { o0[r] *= scl; o1[r] *= scl; }
    }

    const float mC = m_s * C_SCALE;
    float ps = 0.f;
#pragma unroll
    for (int r = 0; r < 16; r++) {
      s0[r] = fast_exp2(fmaf(s0[r], C_SCALE, -mC));
      ps += s0[r];
    }
#pragma unroll
    for (int r = 0; r < 16; r++) {
      s1[r] = fast_exp2(fmaf(s1[r], C_SCALE, -mC));
      ps += s1[r];
    }
    ps += __shfl_xor(ps, 32);
    l_s += ps;

    short8 pf[4];
    pf[0] = mkfrag(s0[0], s0[1], s0[2], s0[3], s0[4], s0[5], s0[6], s0[7]);
    pf[1] = mkfrag(s0[8], s0[9], s0[10], s0[11], s0[12], s0[13], s0[14], s0[15]);
    pf[2] = mkfrag(s1[0], s1[1], s1[2], s1[3], s1[4], s1[5], s1[6], s1[7]);
    pf[3] = mkfrag(s1[8], s1[9], s1[10], s1[11], s1[12], s1[13], s1[14], s1[15]);

    __builtin_amdgcn_s_setprio(1);
#pragma unroll
    for (int ks = 0; ks < 4; ks++) {
      short8 vf0 = *reinterpret_cast<const short8*>(
          ldsp(sVt, swz(l31, ks * 16 + hi * 8)));
      o0 = __builtin_amdgcn_mfma_f32_32x32x16_bf16(vf0, pf[ks], o0, 0, 0, 0);
      short8 vf1 = *reinterpret_cast<const short8*>(
          ldsp(sVt, swz(32 + l31, ks * 16 + hi * 8)));
      o1 = __builtin_amdgcn_mfma_f32_32x32x16_bf16(vf1, pf[ks], o1, 0, 0, 0);
    }
    __builtin_amdgcn_s_setprio(0);

    if (t + 1 < k1) {
      __syncthreads();                 // all waves done reading the buffer
      stage_write(st, sK, sVt, tid);
      __syncthreads();                 // writes visible
    }
  }

  float invl = 1.f / l_s;
  if (chunk < 0) {
    float* op = &out[(size_t)(rowb + qrow) * D_ + h * 64];
#pragma unroll
    for (int rg = 0; rg < 4; rg++) {
      f32x4 v0, v1;
#pragma unroll
      for (int i = 0; i < 4; i++) {
        v0[i] = o0[rg * 4 + i] * invl;
        v1[i] = o1[rg * 4 + i] * invl;
      }
      *reinterpret_cast<f32x4*>(&op[rg * 8 + hi * 4]) = v0;
      *reinterpret_cast<f32x4*>(&op[32 + rg * 8 + hi * 4]) = v1;
    }
  } else {
    const int prow = (bh * 16 + (qt - 16)) * 64 + wid * 32 + l31;
    unsigned short* po = Op + (size_t)chunk * 2097152 + (size_t)prow * 64;
#pragma unroll
    for (int rg = 0; rg < 4; rg++) {
      int d0 = rg * 8 + hi * 4;
      u16x4 a, c;
#pragma unroll
      for (int e = 0; e < 4; e++) {
        a[e] = f2bf(o0[rg * 4 + e] * invl);
        c[e] = f2bf(o1[rg * 4 + e] * invl);
      }
      *reinterpret_cast<u16x4*>(&po[d0]) = a;
      *reinterpret_cast<u16x4*>(&po[32 + d0]) = c;
    }
    if (hi == 0) {
      float2* mlp = (float2*)ML;
      mlp[chunk * 32768 + prow] = make_float2(m_s, l_s);
    }
  }
}

// -------- merge the two k-chunks of strips qt>=16 --------
__global__ __launch_bounds__(256) void merge_kernel(const unsigned short* __restrict__ Op,
                                                    const float* __restrict__ ML,
                                                    float* __restrict__ out) {
  int g = blockIdx.x * 256 + threadIdx.x;   // 131072 = 32768 rows x 4 quarters
  int row = g >> 2, qtr = g & 3;
  int bh = row >> 10, st = (row >> 6) & 15, r = row & 63;
  int b = bh >> 4, h = bh & 15;

  const float2* mlp = (const float2*)ML;
  float2 ml0 = mlp[row];
  float2 ml1 = mlp[32768 + row];
  float mm = fmaxf(ml0.x, ml1.x);
  float w0 = fast_exp2((ml0.x - mm) * C_SCALE) * ml0.y;
  float w1 = fast_exp2((ml1.x - mm) * C_SCALE) * ml1.y;
  float inv = 1.f / (w0 + w1);
  w0 *= inv; w1 *= inv;

  const unsigned short* p0 = Op + (size_t)row * 64 + qtr * 16;
  const unsigned short* p1 = Op + 2097152 + (size_t)row * 64 + qtr * 16;
  int qrow = (16 + st) * 64 + r;
  float* op = &out[(size_t)(b * S_ + qrow) * D_ + h * 64 + qtr * 16];
#pragma unroll
  for (int half = 0; half < 2; half++) {
    u16x8 a = *reinterpret_cast<const u16x8*>(p0 + half * 8);
    u16x8 c = *reinterpret_cast<const u16x8*>(p1 + half * 8);
    f32x4 v0, v1;
#pragma unroll
    for (int e = 0; e < 4; e++) {
      float f0 = __builtin_bit_cast(float, (unsigned int)a[e] << 16);
      float g0 = __builtin_bit_cast(float, (unsigned int)c[e] << 16);
      v0[e] = f0 * w0 + g0 * w1;
      float f1 = __builtin_bit_cast(float, (unsigned int)a[e + 4] << 16);
      float g1 = __builtin_bit_cast(float, (unsigned int)c[e + 4] << 16);
      v1[e] = f1 * w0 + g1 * w1;
    }
    *reinterpret_cast<f32x4*>(&op[half * 8]) = v0;
    *reinterpret_cast<f32x4*>(&op[half * 8 + 4]) = v1;
  }
}

extern "C" void kernel_launch(void* const* d_in, const int* in_sizes, int n_in,
                              void* d_out, int out_size, void* d_ws, size_t ws_size,
                              hipStream_t stream) {
  const float* x    = (const float*)d_in[0];
  const float* W    = (const float*)d_in[1];
  const float* bias = (const float*)d_in[2];
  float* out = (float*)d_out;
  char* ws = (char*)d_ws;
  unsigned short* xb  = (unsigned short*)(ws);                    // 8 MB (reused as Op)
  unsigned short* wt  = (unsigned short*)(ws + (8u << 20));       // 6 MB (reused as ML)
  unsigned short* qk  = (unsigned short*)(ws + (14u << 20));      // 16 MB
  unsigned short* vTb = (unsigned short*)(ws + (30u << 20));      // 8 MB
  unsigned short* Op  = (unsigned short*)(ws);                    // 8 MB, after gemm done
  float* ML           = (float*)(ws + (8u << 20));                // 512 KB, after gemm done

  prep_kernel<<<4864, 256, 0, stream>>>(x, xb, W, wt);
  qkv_gemm_kernel<<<dim3(64, 24), 256, 0, stream>>>(xb, wt, bias, qk, vTb);
  attn_kernel<<<1536, 128, 0, stream>>>(qk, vTb, Op, ML, out);
  merge_kernel<<<512, 256, 0, stream>>>(Op, ML, out);
}